// Round 2
// baseline (622.266 us; speedup 1.0000x reference)
//
#include <hip/hip_runtime.h>
#include <hip/hip_bf16.h>

// BlockLinear: 64 independent GEMMs [4096x256] @ [256x256]^T + bias, fp32 in/out.
// R1: barrier-free streaming kernel. MFMA A/B fragments (8 contiguous k elems
// per lane) are loaded DIRECTLY global->register (fp32), converted to bf16 in
// regs, no LDS at all. A-rows re-read 4x / B-rows 2x by sibling waves -> served
// by same-CU L1 / same-XCD L2; HBM traffic stays ~285 MB read + 268 MB write.
// R0 was latency-bound (2.3 TB/s, all pipes idle) on the load->LDS->barrier chain.

#define BATCH   4096
#define NBLK    64
#define KB_     256              // in_block (K)
#define OB_     256              // out_block (N)
#define XSTRIDE (NBLK * KB_)     // 16384 floats per x row
#define BM      128              // M per workgroup (2 waves)
#define NTHREADS 512             // 8 waves: 2 (M) x 4 (N); each wave 64x64

typedef __attribute__((ext_vector_type(8))) short bf16x8;   // 8 bf16 = 4 VGPRs
typedef __attribute__((ext_vector_type(4))) float f32x4;

__device__ __forceinline__ bf16x8 cvt8(float4 a, float4 b) {
    union { bf16x8 v; __hip_bfloat162 h[4]; } u;
    u.h[0] = __float22bfloat162_rn(make_float2(a.x, a.y));
    u.h[1] = __float22bfloat162_rn(make_float2(a.z, a.w));
    u.h[2] = __float22bfloat162_rn(make_float2(b.x, b.y));
    u.h[3] = __float22bfloat162_rn(make_float2(b.z, b.w));
    return u.v;
}

__global__ __launch_bounds__(NTHREADS, 2)
void blocklinear_kernel(const float* __restrict__ x,
                        const float* __restrict__ w,
                        const float* __restrict__ bias,
                        float* __restrict__ out)
{
    // wg & 63 = block index: block b always lands on XCD b%8, so each XCD's L2
    // holds 8 blocks x 256 KB fp32 weights = 2 MB (fits in 4 MB L2).
    const int wg   = blockIdx.x;
    const int blk  = wg & 63;
    const int m0   = (wg >> 6) * BM;

    const int tid  = threadIdx.x;
    const int lane = tid & 63;
    const int wave = tid >> 6;        // 0..7
    const int wm   = wave >> 2;       // 0..1  (M)
    const int wn   = wave & 3;        // 0..3  (N)
    const int lrow = lane & 15;
    const int kq0  = (lane >> 4) << 3;   // quad*8: this lane's k-offset in a 32-chunk

    // Per-fragment base pointers (k varies in the loop).
    const float* xp[4];
    const float* wp[4];
    #pragma unroll
    for (int f = 0; f < 4; f++) {
        xp[f] = x + (size_t)(m0 + wm * 64 + f * 16 + lrow) * XSTRIDE
                  + (size_t)blk * KB_ + kq0;
        wp[f] = w + (size_t)blk * (OB_ * KB_)
                  + (size_t)(wn * 64 + f * 16 + lrow) * KB_ + kq0;
    }

    f32x4 acc[4][4] = {};             // 64 fp32 accumulators / lane

    #pragma unroll 2
    for (int kb = 0; kb < KB_; kb += 32) {
        bf16x8 af[4], bfr[4];
        #pragma unroll
        for (int f = 0; f < 4; f++) {
            float4 a0 = *(const float4*)(xp[f] + kb);
            float4 a1 = *(const float4*)(xp[f] + kb + 4);
            af[f] = cvt8(a0, a1);
        }
        #pragma unroll
        for (int f = 0; f < 4; f++) {
            float4 b0 = *(const float4*)(wp[f] + kb);
            float4 b1 = *(const float4*)(wp[f] + kb + 4);
            bfr[f] = cvt8(b0, b1);
        }
        #pragma unroll
        for (int fm = 0; fm < 4; fm++)
            #pragma unroll
            for (int fn = 0; fn < 4; fn++)
                acc[fm][fn] = __builtin_amdgcn_mfma_f32_16x16x32_bf16(
                    af[fm], bfr[fn], acc[fm][fn], 0, 0, 0);
    }

    // ---- epilogue: C/D layout col=lane&15, row=quad*4+reg ----
    const int quad = lane >> 4;
    #pragma unroll
    for (int fn = 0; fn < 4; fn++) {
        int col = wn * 64 + fn * 16 + lrow;
        float bv = bias[blk * OB_ + col];
        #pragma unroll
        for (int fm = 0; fm < 4; fm++) {
            #pragma unroll
            for (int r = 0; r < 4; r++) {
                int row = m0 + wm * 64 + fm * 16 + quad * 4 + r;
                out[(size_t)row * (NBLK * OB_) + blk * OB_ + col] = acc[fm][fn][r] + bv;
            }
        }
    }
}

extern "C" void kernel_launch(void* const* d_in, const int* in_sizes, int n_in,
                              void* d_out, int out_size, void* d_ws, size_t ws_size,
                              hipStream_t stream) {
    const float* x    = (const float*)d_in[0];
    const float* w    = (const float*)d_in[1];
    const float* bias = (const float*)d_in[2];
    float* out        = (float*)d_out;

    dim3 grid((BATCH / BM) * NBLK);   // 32 * 64 = 2048 WGs
    dim3 block(NTHREADS);
    blocklinear_kernel<<<grid, block, 0, stream>>>(x, w, bias, out);
}